// Round 1
// baseline (500.312 us; speedup 1.0000x reference)
//
#include <hip/hip_runtime.h>
#include <hip/hip_bf16.h>

#define NN 50000
#define NE 600000
#define DD 128
#define LDSW 136

typedef __bf16 bf16;
typedef __attribute__((ext_vector_type(8))) __bf16 bf16x8;
typedef __attribute__((ext_vector_type(4))) float f32x4;
typedef __attribute__((ext_vector_type(4))) unsigned int u32x4;
typedef unsigned short u16;

// ---------------- edge dtype detect (int32 vs int64 layout) ----------------
__global__ void k_detect(const int* __restrict__ ei, int* __restrict__ flag) {
    __shared__ int any;
    int tid = threadIdx.x;
    if (tid == 0) any = 0;
    __syncthreads();
    // if data is int64 (little-endian, values < 2^31), every odd 32-bit word is 0
    if (ei[2 * tid + 1] != 0) atomicAdd(&any, 1);
    __syncthreads();
    if (tid == 0) flag[0] = (any == 0) ? 1 : 0;  // 1 => int64 layout
}

__device__ __forceinline__ int edge_dst(const int* ei, int e, int f) {
    return f ? ei[2 * NE + 2 * e] : ei[NE + e];
}
__device__ __forceinline__ int edge_src(const int* ei, int e, int f) {
    return f ? ei[2 * e] : ei[e];
}

// ---------------- CSR build ----------------
__global__ void k_degree(const int* __restrict__ ei, const int* __restrict__ flag,
                         int* __restrict__ deg) {
    int i = blockIdx.x * blockDim.x + threadIdx.x;
    if (i < NE) {
        int f = flag[0];
        atomicAdd(&deg[edge_dst(ei, i, f)], 1);
    }
}

__global__ __launch_bounds__(1024) void k_scan(const int* __restrict__ deg,
                                               int* __restrict__ row_start,
                                               int* __restrict__ cursor) {
    const int T = 1024;
    int tid = threadIdx.x;
    const int per = (NN + T - 1) / T;  // 49
    int s0 = tid * per;
    int s1 = s0 + per; if (s1 > NN) s1 = NN;
    int s = 0;
    for (int i = s0; i < s1; i++) s += deg[i];
    __shared__ int sm[T];
    sm[tid] = s;
    __syncthreads();
    for (int off = 1; off < T; off <<= 1) {
        int v = (tid >= off) ? sm[tid - off] : 0;
        __syncthreads();
        sm[tid] += v;
        __syncthreads();
    }
    int run = (tid == 0) ? 0 : sm[tid - 1];
    for (int i = s0; i < s1; i++) {
        row_start[i] = run;
        cursor[i] = run;
        run += deg[i];
    }
    if (tid == 0) row_start[NN] = sm[T - 1];
}

__global__ void k_fill(const int* __restrict__ ei, const int* __restrict__ flag,
                       int* __restrict__ cursor, int* __restrict__ adj) {
    int i = blockIdx.x * blockDim.x + threadIdx.x;
    if (i < NE) {
        int f = flag[0];
        int d = edge_dst(ei, i, f);
        int p = atomicAdd(&cursor[d], 1);
        adj[p] = edge_src(ei, i, f);
    }
}

// ---------------- weight convert: wt[n][k] = bf16(w[k][n]) ----------------
struct Ptr8 { const float* p[8]; };

__global__ void k_wconv(Ptr8 ws, u16* __restrict__ wt) {
    int m = blockIdx.y;        // matrix 0..7
    int n = blockIdx.x;        // 0..127 (output col)
    int k = threadIdx.x;       // 0..127
    const float* w = ws.p[m];
    bf16 b = (bf16)w[k * DD + n];
    wt[(size_t)m * DD * DD + n * DD + k] = __builtin_bit_cast(u16, b);
}

// ---------------- aggregation: out = bf16(x[v] + sum_{u in N(v)} x[u]) ----------------
__global__ __launch_bounds__(256) void k_agg(const float* __restrict__ x,
                                             const int* __restrict__ row_start,
                                             const int* __restrict__ adj,
                                             u16* __restrict__ out) {
    int gid = blockIdx.x * blockDim.x + threadIdx.x;
    int node = gid >> 6, lane = gid & 63;
    if (node >= NN) return;
    const float2* base = (const float2*)x;  // 64 float2 per row
    float2 a = base[(size_t)node * 64 + lane];
    float2 a1 = {0.f, 0.f};
    int s = row_start[node], e = row_start[node + 1];
    int i = s;
    for (; i + 1 < e; i += 2) {
        float2 t0 = base[(size_t)adj[i] * 64 + lane];
        float2 t1 = base[(size_t)adj[i + 1] * 64 + lane];
        a.x += t0.x; a.y += t0.y;
        a1.x += t1.x; a1.y += t1.y;
    }
    if (i < e) {
        float2 t = base[(size_t)adj[i] * 64 + lane];
        a.x += t.x; a.y += t.y;
    }
    a.x += a1.x; a.y += a1.y;
    bf16 bx = (bf16)a.x, by = (bf16)a.y;
    unsigned int pk = (unsigned int)__builtin_bit_cast(u16, bx) |
                      ((unsigned int)__builtin_bit_cast(u16, by) << 16);
    *(unsigned int*)(out + (size_t)node * DD + lane * 2) = pk;
}

// ---------------- fused MLP (+LN+relu) per 128-node tile ----------------
template <bool LN>
__global__ __launch_bounds__(256) void k_mlp(const u16* __restrict__ hin,
                                             const u16* __restrict__ w1t,
                                             const float* __restrict__ b1,
                                             const u16* __restrict__ w2t,
                                             const float* __restrict__ b2,
                                             const float* __restrict__ g,
                                             const float* __restrict__ bta,
                                             float* __restrict__ hout) {
    __shared__ u16 lds[128 * LDSW];
    const int tid = threadIdx.x;
    const int wv = tid >> 6, lane = tid & 63;
    const int l15 = lane & 15, l4 = lane >> 4;
    const int tile0 = blockIdx.x * 128;

    // stage input tile (zero-pad invalid rows)
#pragma unroll
    for (int it = 0; it < 8; ++it) {
        int slot = tid + it * 256;
        int row = slot >> 4, c16 = slot & 15;
        u32x4 v = {0u, 0u, 0u, 0u};
        int grow = tile0 + row;
        if (grow < NN) v = *(const u32x4*)(hin + (size_t)grow * DD + c16 * 8);
        *(u32x4*)&lds[row * LDSW + c16 * 8] = v;
    }
    __syncthreads();

    // per-lane column constants
    float b1c[8], b2c[8], gc[8], bc[8];
#pragma unroll
    for (int c = 0; c < 8; c++) {
        int col = c * 16 + l15;
        b1c[c] = b1[col];
        b2c[c] = b2[col];
        if (LN) { gc[c] = g[col]; bc[c] = bta[col]; }
    }

    f32x4 acc[2][8];
#pragma unroll
    for (int r = 0; r < 2; r++)
#pragma unroll
        for (int c = 0; c < 8; c++) acc[r][c] = (f32x4){0.f, 0.f, 0.f, 0.f};

    const int rowbase = wv * 32;

    // GEMM1: h1 = relu(A @ W1 + b1)
#pragma unroll
    for (int ks = 0; ks < 4; ++ks) {
        bf16x8 a0 = __builtin_bit_cast(bf16x8,
            *(const u32x4*)&lds[(rowbase + l15) * LDSW + ks * 32 + l4 * 8]);
        bf16x8 a1 = __builtin_bit_cast(bf16x8,
            *(const u32x4*)&lds[(rowbase + 16 + l15) * LDSW + ks * 32 + l4 * 8]);
#pragma unroll
        for (int c = 0; c < 8; c++) {
            bf16x8 b = __builtin_bit_cast(bf16x8,
                *(const u32x4*)(w1t + (size_t)(c * 16 + l15) * DD + ks * 32 + l4 * 8));
            acc[0][c] = __builtin_amdgcn_mfma_f32_16x16x32_bf16(a0, b, acc[0][c], 0, 0, 0);
            acc[1][c] = __builtin_amdgcn_mfma_f32_16x16x32_bf16(a1, b, acc[1][c], 0, 0, 0);
        }
    }

    // write h1 (bf16) back into the same LDS tile (wave-private rows)
#pragma unroll
    for (int r = 0; r < 2; r++) {
#pragma unroll
        for (int c = 0; c < 8; c++) {
            int col = c * 16 + l15;
#pragma unroll
            for (int j = 0; j < 4; j++) {
                float v = acc[r][c][j] + b1c[c];
                v = v > 0.f ? v : 0.f;
                bf16 b = (bf16)v;
                int row = rowbase + r * 16 + l4 * 4 + j;
                lds[row * LDSW + col] = __builtin_bit_cast(u16, b);
            }
        }
    }
    __syncthreads();  // safety (rows are wave-private; cheap)

#pragma unroll
    for (int r = 0; r < 2; r++)
#pragma unroll
        for (int c = 0; c < 8; c++) acc[r][c] = (f32x4){0.f, 0.f, 0.f, 0.f};

    // GEMM2: h2 = h1 @ W2 + b2
#pragma unroll
    for (int ks = 0; ks < 4; ++ks) {
        bf16x8 a0 = __builtin_bit_cast(bf16x8,
            *(const u32x4*)&lds[(rowbase + l15) * LDSW + ks * 32 + l4 * 8]);
        bf16x8 a1 = __builtin_bit_cast(bf16x8,
            *(const u32x4*)&lds[(rowbase + 16 + l15) * LDSW + ks * 32 + l4 * 8]);
#pragma unroll
        for (int c = 0; c < 8; c++) {
            bf16x8 b = __builtin_bit_cast(bf16x8,
                *(const u32x4*)(w2t + (size_t)(c * 16 + l15) * DD + ks * 32 + l4 * 8));
            acc[0][c] = __builtin_amdgcn_mfma_f32_16x16x32_bf16(a0, b, acc[0][c], 0, 0, 0);
            acc[1][c] = __builtin_amdgcn_mfma_f32_16x16x32_bf16(a1, b, acc[1][c], 0, 0, 0);
        }
    }

    // epilogue: +b2, optional LN(+g,beta)+relu, store fp32
#pragma unroll
    for (int r = 0; r < 2; r++) {
        float vals[8][4];
#pragma unroll
        for (int c = 0; c < 8; c++)
#pragma unroll
            for (int j = 0; j < 4; j++) vals[c][j] = acc[r][c][j] + b2c[c];

        if (LN) {
            float s[4], q[4];
#pragma unroll
            for (int j = 0; j < 4; j++) {
                s[j] = 0.f; q[j] = 0.f;
#pragma unroll
                for (int c = 0; c < 8; c++) {
                    s[j] += vals[c][j];
                    q[j] += vals[c][j] * vals[c][j];
                }
            }
#pragma unroll
            for (int m = 1; m <= 8; m <<= 1) {
#pragma unroll
                for (int j = 0; j < 4; j++) {
                    s[j] += __shfl_xor(s[j], m);
                    q[j] += __shfl_xor(q[j], m);
                }
            }
#pragma unroll
            for (int j = 0; j < 4; j++) {
                float mu = s[j] * (1.f / 128.f);
                float var = q[j] * (1.f / 128.f) - mu * mu;
                float rs = rsqrtf(var + 1e-5f);
#pragma unroll
                for (int c = 0; c < 8; c++) {
                    float v = (vals[c][j] - mu) * rs * gc[c] + bc[c];
                    vals[c][j] = v > 0.f ? v : 0.f;
                }
            }
        }

#pragma unroll
        for (int c = 0; c < 8; c++) {
            int col = c * 16 + l15;
#pragma unroll
            for (int j = 0; j < 4; j++) {
                int row = tile0 + rowbase + r * 16 + l4 * 4 + j;
                if (row < NN) hout[(size_t)row * DD + col] = vals[c][j];
            }
        }
    }
}

// ---------------- launch ----------------
extern "C" void kernel_launch(void* const* d_in, const int* in_sizes, int n_in,
                              void* d_out, int out_size, void* d_ws, size_t ws_size,
                              hipStream_t stream) {
    const float* x = (const float*)d_in[0];
    const int* ei = (const int*)d_in[1];
    const float* w1[4]; const float* b1[4]; const float* w2[4]; const float* b2[4];
    for (int i = 0; i < 4; i++) {
        w1[i] = (const float*)d_in[2 + 4 * i];
        b1[i] = (const float*)d_in[3 + 4 * i];
        w2[i] = (const float*)d_in[4 + 4 * i];
        b2[i] = (const float*)d_in[5 + 4 * i];
    }
    const float* g[3]; const float* bt[3];
    for (int i = 0; i < 3; i++) {
        g[i] = (const float*)d_in[18 + 2 * i];
        bt[i] = (const float*)d_in[19 + 2 * i];
    }

    char* ws = (char*)d_ws;
    size_t off = 0;
    auto alloc = [&](size_t bytes) -> char* {
        char* p = ws + off;
        off = (off + bytes + 255) & ~(size_t)255;
        return p;
    };
    int* flag      = (int*)alloc(4);
    int* row_start = (int*)alloc((NN + 1) * 4);
    int* deg       = (int*)alloc(NN * 4);
    int* cursor    = (int*)alloc(NN * 4);
    int* adj       = (int*)alloc(NE * 4);
    u16* wt        = (u16*)alloc((size_t)8 * DD * DD * 2);
    u16* hbf       = (u16*)alloc((size_t)NN * DD * 2);
    float* hA      = (float*)alloc((size_t)NN * DD * 4);
    float* hB      = (float*)alloc((size_t)NN * DD * 4);

    hipMemsetAsync(deg, 0, NN * 4, stream);
    k_detect<<<1, 256, 0, stream>>>(ei, flag);
    k_degree<<<(NE + 255) / 256, 256, 0, stream>>>(ei, flag, deg);
    k_scan<<<1, 1024, 0, stream>>>(deg, row_start, cursor);
    k_fill<<<(NE + 255) / 256, 256, 0, stream>>>(ei, flag, cursor, adj);

    Ptr8 p8;
    for (int i = 0; i < 4; i++) {
        p8.p[2 * i] = w1[i];
        p8.p[2 * i + 1] = w2[i];
    }
    k_wconv<<<dim3(128, 8), 128, 0, stream>>>(p8, wt);

    const float* hin = x;
    for (int i = 0; i < 4; i++) {
        k_agg<<<(NN * 64 + 255) / 256, 256, 0, stream>>>(hin, row_start, adj, hbf);
        float* outp = (i == 3) ? (float*)d_out : ((i & 1) ? hB : hA);
        const u16* w1ti = wt + (size_t)(2 * i) * DD * DD;
        const u16* w2ti = wt + (size_t)(2 * i + 1) * DD * DD;
        if (i < 3)
            k_mlp<true><<<(NN + 127) / 128, 256, 0, stream>>>(hbf, w1ti, b1[i], w2ti, b2[i],
                                                              g[i], bt[i], outp);
        else
            k_mlp<false><<<(NN + 127) / 128, 256, 0, stream>>>(hbf, w1ti, b1[i], w2ti, b2[i],
                                                               nullptr, nullptr, outp);
        hin = outp;
    }
}

// Round 2
// 401.154 us; speedup vs baseline: 1.2472x; 1.2472x over previous
//
#include <hip/hip_runtime.h>
#include <hip/hip_bf16.h>

#define NN 50000
#define NE 600000
#define DD 128
#define LDSW 136
#define SC 256
#define NCH ((NN + SC - 1) / SC)  // 196

typedef __bf16 bf16;
typedef __attribute__((ext_vector_type(8))) __bf16 bf16x8;
typedef __attribute__((ext_vector_type(4))) float f32x4;
typedef __attribute__((ext_vector_type(4))) unsigned int u32x4;
typedef unsigned short u16;

// ---------------- edge dtype detect (int32 vs int64 layout) ----------------
__global__ void k_detect(const int* __restrict__ ei, int* __restrict__ flag) {
    __shared__ int any;
    int tid = threadIdx.x;
    if (tid == 0) any = 0;
    __syncthreads();
    // if data is int64 (little-endian, values < 2^31), every odd 32-bit word is 0
    if (ei[2 * tid + 1] != 0) atomicAdd(&any, 1);
    __syncthreads();
    if (tid == 0) flag[0] = (any == 0) ? 1 : 0;  // 1 => int64 layout
}

__device__ __forceinline__ int edge_dst(const int* ei, int e, int f) {
    return f ? ei[2 * NE + 2 * e] : ei[NE + e];
}
__device__ __forceinline__ int edge_src(const int* ei, int e, int f) {
    return f ? ei[2 * e] : ei[e];
}

// ---------------- CSR build ----------------
__global__ void k_degree(const int* __restrict__ ei, const int* __restrict__ flag,
                         int* __restrict__ deg) {
    int i = blockIdx.x * blockDim.x + threadIdx.x;
    if (i < NE) {
        int f = flag[0];
        atomicAdd(&deg[edge_dst(ei, i, f)], 1);
    }
}

// hierarchical scan: (1) per-chunk reduce, (2) scan of 196 partials, (3) distribute
__global__ __launch_bounds__(256) void k_scan1(const int* __restrict__ deg,
                                               int* __restrict__ partial) {
    int b = blockIdx.x, tid = threadIdx.x;
    int i = b * SC + tid;
    int v = (i < NN) ? deg[i] : 0;
#pragma unroll
    for (int off = 1; off < 64; off <<= 1) v += __shfl_xor(v, off);
    __shared__ int sm[4];
    if ((tid & 63) == 0) sm[tid >> 6] = v;
    __syncthreads();
    if (tid == 0) partial[b] = sm[0] + sm[1] + sm[2] + sm[3];
}

__global__ __launch_bounds__(256) void k_scan2(const int* __restrict__ partial,
                                               int* __restrict__ chunk_off) {
    int tid = threadIdx.x;
    int lane = tid & 63, w = tid >> 6;
    int v = (tid < NCH) ? partial[tid] : 0;
    int orig = v;
#pragma unroll
    for (int off = 1; off < 64; off <<= 1) {
        int t = __shfl_up(v, off);
        if (lane >= off) v += t;
    }
    __shared__ int sm[4];
    if (lane == 63) sm[w] = v;
    __syncthreads();
    int add = 0;
    for (int k = 0; k < w; k++) add += sm[k];
    v += add;
    if (tid < NCH) chunk_off[tid] = v - orig;  // exclusive prefix
}

__global__ __launch_bounds__(256) void k_scan3(const int* __restrict__ deg,
                                               const int* __restrict__ chunk_off,
                                               int* __restrict__ row_start,
                                               int* __restrict__ cursor) {
    int b = blockIdx.x, tid = threadIdx.x;
    int i = b * SC + tid;
    int lane = tid & 63, w = tid >> 6;
    int v = (i < NN) ? deg[i] : 0;
    int orig = v;
#pragma unroll
    for (int off = 1; off < 64; off <<= 1) {
        int t = __shfl_up(v, off);
        if (lane >= off) v += t;
    }
    __shared__ int sm[4];
    if (lane == 63) sm[w] = v;
    __syncthreads();
    int add = chunk_off[b];
    for (int k = 0; k < w; k++) add += sm[k];
    int ex = v - orig + add;
    if (i < NN) { row_start[i] = ex; cursor[i] = ex; }
    if (b == 0 && tid == 0) row_start[NN] = NE;  // total degree == edge count
}

__global__ void k_fill(const int* __restrict__ ei, const int* __restrict__ flag,
                       int* __restrict__ cursor, int* __restrict__ adj) {
    int i = blockIdx.x * blockDim.x + threadIdx.x;
    if (i < NE) {
        int f = flag[0];
        int d = edge_dst(ei, i, f);
        int p = atomicAdd(&cursor[d], 1);
        adj[p] = edge_src(ei, i, f);
    }
}

// ---------------- weight convert: wt[n][k] = bf16(w[k][n]) ----------------
struct Ptr8 { const float* p[8]; };

__global__ void k_wconv(Ptr8 ws, u16* __restrict__ wt) {
    int m = blockIdx.y;        // matrix 0..7
    int n = blockIdx.x;        // 0..127 (output col)
    int k = threadIdx.x;       // 0..127
    const float* w = ws.p[m];
    bf16 b = (bf16)w[k * DD + n];
    wt[(size_t)m * DD * DD + n * DD + k] = __builtin_bit_cast(u16, b);
}

// ---------------- aggregation: out = bf16(x[v] + sum_{u in N(v)} x[u]) ----------------
__global__ __launch_bounds__(256) void k_agg(const float* __restrict__ x,
                                             const int* __restrict__ row_start,
                                             const int* __restrict__ adj,
                                             u16* __restrict__ out) {
    int gid = blockIdx.x * blockDim.x + threadIdx.x;
    int node = gid >> 6, lane = gid & 63;
    if (node >= NN) return;
    const float2* base = (const float2*)x;  // 64 float2 per row
    float2 a = base[(size_t)node * 64 + lane];
    float2 a1 = {0.f, 0.f};
    int s = row_start[node], e = row_start[node + 1];
    int i = s;
    for (; i + 1 < e; i += 2) {
        float2 t0 = base[(size_t)adj[i] * 64 + lane];
        float2 t1 = base[(size_t)adj[i + 1] * 64 + lane];
        a.x += t0.x; a.y += t0.y;
        a1.x += t1.x; a1.y += t1.y;
    }
    if (i < e) {
        float2 t = base[(size_t)adj[i] * 64 + lane];
        a.x += t.x; a.y += t.y;
    }
    a.x += a1.x; a.y += a1.y;
    bf16 bx = (bf16)a.x, by = (bf16)a.y;
    unsigned int pk = (unsigned int)__builtin_bit_cast(u16, bx) |
                      ((unsigned int)__builtin_bit_cast(u16, by) << 16);
    *(unsigned int*)(out + (size_t)node * DD + lane * 2) = pk;
}

// ---------------- fused MLP (+LN+relu) per 128-node tile ----------------
template <bool LN>
__global__ __launch_bounds__(256) void k_mlp(const u16* __restrict__ hin,
                                             const u16* __restrict__ w1t,
                                             const float* __restrict__ b1,
                                             const u16* __restrict__ w2t,
                                             const float* __restrict__ b2,
                                             const float* __restrict__ g,
                                             const float* __restrict__ bta,
                                             float* __restrict__ hout) {
    __shared__ u16 lds[128 * LDSW];
    const int tid = threadIdx.x;
    const int wv = tid >> 6, lane = tid & 63;
    const int l15 = lane & 15, l4 = lane >> 4;
    const int tile0 = blockIdx.x * 128;

    // stage input tile (zero-pad invalid rows)
#pragma unroll
    for (int it = 0; it < 8; ++it) {
        int slot = tid + it * 256;
        int row = slot >> 4, c16 = slot & 15;
        u32x4 v = {0u, 0u, 0u, 0u};
        int grow = tile0 + row;
        if (grow < NN) v = *(const u32x4*)(hin + (size_t)grow * DD + c16 * 8);
        *(u32x4*)&lds[row * LDSW + c16 * 8] = v;
    }
    __syncthreads();

    // per-lane column constants
    float b1c[8], b2c[8], gc[8], bc[8];
#pragma unroll
    for (int c = 0; c < 8; c++) {
        int col = c * 16 + l15;
        b1c[c] = b1[col];
        b2c[c] = b2[col];
        if (LN) { gc[c] = g[col]; bc[c] = bta[col]; }
    }

    f32x4 acc[2][8];
#pragma unroll
    for (int r = 0; r < 2; r++)
#pragma unroll
        for (int c = 0; c < 8; c++) acc[r][c] = (f32x4){0.f, 0.f, 0.f, 0.f};

    const int rowbase = wv * 32;

    // GEMM1: h1 = relu(A @ W1 + b1)
#pragma unroll
    for (int ks = 0; ks < 4; ++ks) {
        bf16x8 a0 = __builtin_bit_cast(bf16x8,
            *(const u32x4*)&lds[(rowbase + l15) * LDSW + ks * 32 + l4 * 8]);
        bf16x8 a1 = __builtin_bit_cast(bf16x8,
            *(const u32x4*)&lds[(rowbase + 16 + l15) * LDSW + ks * 32 + l4 * 8]);
#pragma unroll
        for (int c = 0; c < 8; c++) {
            bf16x8 b = __builtin_bit_cast(bf16x8,
                *(const u32x4*)(w1t + (size_t)(c * 16 + l15) * DD + ks * 32 + l4 * 8));
            acc[0][c] = __builtin_amdgcn_mfma_f32_16x16x32_bf16(a0, b, acc[0][c], 0, 0, 0);
            acc[1][c] = __builtin_amdgcn_mfma_f32_16x16x32_bf16(a1, b, acc[1][c], 0, 0, 0);
        }
    }

    // write h1 (bf16) back into the same LDS tile (wave-private rows)
#pragma unroll
    for (int r = 0; r < 2; r++) {
#pragma unroll
        for (int c = 0; c < 8; c++) {
            int col = c * 16 + l15;
#pragma unroll
            for (int j = 0; j < 4; j++) {
                float v = acc[r][c][j] + b1c[c];
                v = v > 0.f ? v : 0.f;
                bf16 b = (bf16)v;
                int row = rowbase + r * 16 + l4 * 4 + j;
                lds[row * LDSW + col] = __builtin_bit_cast(u16, b);
            }
        }
    }
    __syncthreads();  // safety (rows are wave-private; cheap)

#pragma unroll
    for (int r = 0; r < 2; r++)
#pragma unroll
        for (int c = 0; c < 8; c++) acc[r][c] = (f32x4){0.f, 0.f, 0.f, 0.f};

    // GEMM2: h2 = h1 @ W2 + b2
#pragma unroll
    for (int ks = 0; ks < 4; ++ks) {
        bf16x8 a0 = __builtin_bit_cast(bf16x8,
            *(const u32x4*)&lds[(rowbase + l15) * LDSW + ks * 32 + l4 * 8]);
        bf16x8 a1 = __builtin_bit_cast(bf16x8,
            *(const u32x4*)&lds[(rowbase + 16 + l15) * LDSW + ks * 32 + l4 * 8]);
#pragma unroll
        for (int c = 0; c < 8; c++) {
            bf16x8 b = __builtin_bit_cast(bf16x8,
                *(const u32x4*)(w2t + (size_t)(c * 16 + l15) * DD + ks * 32 + l4 * 8));
            acc[0][c] = __builtin_amdgcn_mfma_f32_16x16x32_bf16(a0, b, acc[0][c], 0, 0, 0);
            acc[1][c] = __builtin_amdgcn_mfma_f32_16x16x32_bf16(a1, b, acc[1][c], 0, 0, 0);
        }
    }

    // epilogue: +b2, optional LN(+g,beta)+relu, store fp32
#pragma unroll
    for (int r = 0; r < 2; r++) {
        float vals[8][4];
#pragma unroll
        for (int c = 0; c < 8; c++)
#pragma unroll
            for (int j = 0; j < 4; j++) vals[c][j] = acc[r][c][j] + b2c[c];

        if (LN) {
            float s[4], q[4];
#pragma unroll
            for (int j = 0; j < 4; j++) {
                s[j] = 0.f; q[j] = 0.f;
#pragma unroll
                for (int c = 0; c < 8; c++) {
                    s[j] += vals[c][j];
                    q[j] += vals[c][j] * vals[c][j];
                }
            }
#pragma unroll
            for (int m = 1; m <= 8; m <<= 1) {
#pragma unroll
                for (int j = 0; j < 4; j++) {
                    s[j] += __shfl_xor(s[j], m);
                    q[j] += __shfl_xor(q[j], m);
                }
            }
#pragma unroll
            for (int j = 0; j < 4; j++) {
                float mu = s[j] * (1.f / 128.f);
                float var = q[j] * (1.f / 128.f) - mu * mu;
                float rs = rsqrtf(var + 1e-5f);
#pragma unroll
                for (int c = 0; c < 8; c++) {
                    float v = (vals[c][j] - mu) * rs * gc[c] + bc[c];
                    vals[c][j] = v > 0.f ? v : 0.f;
                }
            }
        }

#pragma unroll
        for (int c = 0; c < 8; c++) {
            int col = c * 16 + l15;
#pragma unroll
            for (int j = 0; j < 4; j++) {
                int row = tile0 + rowbase + r * 16 + l4 * 4 + j;
                if (row < NN) hout[(size_t)row * DD + col] = vals[c][j];
            }
        }
    }
}

// ---------------- launch ----------------
extern "C" void kernel_launch(void* const* d_in, const int* in_sizes, int n_in,
                              void* d_out, int out_size, void* d_ws, size_t ws_size,
                              hipStream_t stream) {
    const float* x = (const float*)d_in[0];
    const int* ei = (const int*)d_in[1];
    const float* w1[4]; const float* b1[4]; const float* w2[4]; const float* b2[4];
    for (int i = 0; i < 4; i++) {
        w1[i] = (const float*)d_in[2 + 4 * i];
        b1[i] = (const float*)d_in[3 + 4 * i];
        w2[i] = (const float*)d_in[4 + 4 * i];
        b2[i] = (const float*)d_in[5 + 4 * i];
    }
    const float* g[3]; const float* bt[3];
    for (int i = 0; i < 3; i++) {
        g[i] = (const float*)d_in[18 + 2 * i];
        bt[i] = (const float*)d_in[19 + 2 * i];
    }

    char* ws = (char*)d_ws;
    size_t off = 0;
    auto alloc = [&](size_t bytes) -> char* {
        char* p = ws + off;
        off = (off + bytes + 255) & ~(size_t)255;
        return p;
    };
    int* flag      = (int*)alloc(4);
    int* row_start = (int*)alloc((NN + 1) * 4);
    int* deg       = (int*)alloc(NN * 4);
    int* cursor    = (int*)alloc(NN * 4);
    int* adj       = (int*)alloc(NE * 4);
    int* partial   = (int*)alloc(NCH * 4);
    int* chunk_off = (int*)alloc(NCH * 4);
    u16* wt        = (u16*)alloc((size_t)8 * DD * DD * 2);
    u16* hbf       = (u16*)alloc((size_t)NN * DD * 2);
    float* hA      = (float*)alloc((size_t)NN * DD * 4);
    float* hB      = (float*)alloc((size_t)NN * DD * 4);

    hipMemsetAsync(deg, 0, NN * 4, stream);
    k_detect<<<1, 256, 0, stream>>>(ei, flag);
    k_degree<<<(NE + 255) / 256, 256, 0, stream>>>(ei, flag, deg);
    k_scan1<<<NCH, 256, 0, stream>>>(deg, partial);
    k_scan2<<<1, 256, 0, stream>>>(partial, chunk_off);
    k_scan3<<<NCH, 256, 0, stream>>>(deg, chunk_off, row_start, cursor);
    k_fill<<<(NE + 255) / 256, 256, 0, stream>>>(ei, flag, cursor, adj);

    Ptr8 p8;
    for (int i = 0; i < 4; i++) {
        p8.p[2 * i] = w1[i];
        p8.p[2 * i + 1] = w2[i];
    }
    k_wconv<<<dim3(128, 8), 128, 0, stream>>>(p8, wt);

    const float* hin = x;
    for (int i = 0; i < 4; i++) {
        k_agg<<<(NN * 64 + 255) / 256, 256, 0, stream>>>(hin, row_start, adj, hbf);
        float* outp = (i == 3) ? (float*)d_out : ((i & 1) ? hB : hA);
        const u16* w1ti = wt + (size_t)(2 * i) * DD * DD;
        const u16* w2ti = wt + (size_t)(2 * i + 1) * DD * DD;
        if (i < 3)
            k_mlp<true><<<(NN + 127) / 128, 256, 0, stream>>>(hbf, w1ti, b1[i], w2ti, b2[i],
                                                              g[i], bt[i], outp);
        else
            k_mlp<false><<<(NN + 127) / 128, 256, 0, stream>>>(hbf, w1ti, b1[i], w2ti, b2[i],
                                                               nullptr, nullptr, outp);
        hin = outp;
    }
}

// Round 3
// 304.201 us; speedup vs baseline: 1.6447x; 1.3187x over previous
//
#include <hip/hip_runtime.h>
#include <hip/hip_bf16.h>

#define NN 50000
#define NE 600000
#define DD 128
#define LDSW 136
#define SC 256
#define NCH ((NN + SC - 1) / SC)  // 196

typedef __bf16 bf16;
typedef __attribute__((ext_vector_type(8))) __bf16 bf16x8;
typedef __attribute__((ext_vector_type(4))) float f32x4;
typedef __attribute__((ext_vector_type(4))) unsigned int u32x4;
typedef __attribute__((ext_vector_type(4))) unsigned short u16x4;
typedef unsigned short u16;

__device__ __forceinline__ float bf_lo(unsigned int u) {
    return __builtin_bit_cast(float, u << 16);
}
__device__ __forceinline__ float bf_hi(unsigned int u) {
    return __builtin_bit_cast(float, u & 0xffff0000u);
}
__device__ __forceinline__ unsigned int bf_pack(float x, float y) {
    u16 a = __builtin_bit_cast(u16, (bf16)x);
    u16 b = __builtin_bit_cast(u16, (bf16)y);
    return (unsigned int)a | ((unsigned int)b << 16);
}

// ---------------- edge dtype detect (int32 vs int64 layout) ----------------
__global__ void k_detect(const int* __restrict__ ei, int* __restrict__ flag) {
    __shared__ int any;
    int tid = threadIdx.x;
    if (tid == 0) any = 0;
    __syncthreads();
    if (ei[2 * tid + 1] != 0) atomicAdd(&any, 1);
    __syncthreads();
    if (tid == 0) flag[0] = (any == 0) ? 1 : 0;  // 1 => int64 layout
}

__device__ __forceinline__ int edge_dst(const int* ei, int e, int f) {
    return f ? ei[2 * NE + 2 * e] : ei[NE + e];
}
__device__ __forceinline__ int edge_src(const int* ei, int e, int f) {
    return f ? ei[2 * e] : ei[e];
}

// ---------------- CSR build ----------------
__global__ void k_degree(const int* __restrict__ ei, const int* __restrict__ flag,
                         int* __restrict__ deg) {
    int i = blockIdx.x * blockDim.x + threadIdx.x;
    if (i < NE) {
        int f = flag[0];
        atomicAdd(&deg[edge_dst(ei, i, f)], 1);
    }
}

__global__ __launch_bounds__(256) void k_scan1(const int* __restrict__ deg,
                                               int* __restrict__ partial) {
    int b = blockIdx.x, tid = threadIdx.x;
    int i = b * SC + tid;
    int v = (i < NN) ? deg[i] : 0;
#pragma unroll
    for (int off = 1; off < 64; off <<= 1) v += __shfl_xor(v, off);
    __shared__ int sm[4];
    if ((tid & 63) == 0) sm[tid >> 6] = v;
    __syncthreads();
    if (tid == 0) partial[b] = sm[0] + sm[1] + sm[2] + sm[3];
}

__global__ __launch_bounds__(256) void k_scan2(const int* __restrict__ partial,
                                               int* __restrict__ chunk_off) {
    int tid = threadIdx.x;
    int lane = tid & 63, w = tid >> 6;
    int v = (tid < NCH) ? partial[tid] : 0;
    int orig = v;
#pragma unroll
    for (int off = 1; off < 64; off <<= 1) {
        int t = __shfl_up(v, off);
        if (lane >= off) v += t;
    }
    __shared__ int sm[4];
    if (lane == 63) sm[w] = v;
    __syncthreads();
    int add = 0;
    for (int k = 0; k < w; k++) add += sm[k];
    v += add;
    if (tid < NCH) chunk_off[tid] = v - orig;  // exclusive prefix
}

__global__ __launch_bounds__(256) void k_scan3(const int* __restrict__ deg,
                                               const int* __restrict__ chunk_off,
                                               int* __restrict__ row_start,
                                               int* __restrict__ cursor) {
    int b = blockIdx.x, tid = threadIdx.x;
    int i = b * SC + tid;
    int lane = tid & 63, w = tid >> 6;
    int v = (i < NN) ? deg[i] : 0;
    int orig = v;
#pragma unroll
    for (int off = 1; off < 64; off <<= 1) {
        int t = __shfl_up(v, off);
        if (lane >= off) v += t;
    }
    __shared__ int sm[4];
    if (lane == 63) sm[w] = v;
    __syncthreads();
    int add = chunk_off[b];
    for (int k = 0; k < w; k++) add += sm[k];
    int ex = v - orig + add;
    if (i < NN) { row_start[i] = ex; cursor[i] = ex; }
    if (b == 0 && tid == 0) row_start[NN] = NE;
}

__global__ void k_fill(const int* __restrict__ ei, const int* __restrict__ flag,
                       int* __restrict__ cursor, int* __restrict__ adj) {
    int i = blockIdx.x * blockDim.x + threadIdx.x;
    if (i < NE) {
        int f = flag[0];
        int d = edge_dst(ei, i, f);
        int p = atomicAdd(&cursor[d], 1);
        adj[p] = edge_src(ei, i, f);
    }
}

// ---------------- x -> bf16 ----------------
__global__ __launch_bounds__(256) void k_xconv(const float* __restrict__ x,
                                               u16* __restrict__ xb) {
    int i = blockIdx.x * blockDim.x + threadIdx.x;  // per 4 floats
    if (i >= NN * DD / 4) return;
    f32x4 v = *(const f32x4*)(x + (size_t)i * 4);
    u16x4 o;
    o.x = __builtin_bit_cast(u16, (bf16)v.x);
    o.y = __builtin_bit_cast(u16, (bf16)v.y);
    o.z = __builtin_bit_cast(u16, (bf16)v.z);
    o.w = __builtin_bit_cast(u16, (bf16)v.w);
    *(u16x4*)(xb + (size_t)i * 4) = o;
}

// ---------------- weight convert: wt[n][k] = bf16(w[k][n]) ----------------
struct Ptr8 { const float* p[8]; };

__global__ void k_wconv(Ptr8 ws, u16* __restrict__ wt) {
    int m = blockIdx.y;
    int n = blockIdx.x;
    int k = threadIdx.x;
    const float* w = ws.p[m];
    bf16 b = (bf16)w[k * DD + n];
    wt[(size_t)m * DD * DD + n * DD + k] = __builtin_bit_cast(u16, b);
}

// ---------------- aggregation (bf16 in, bf16 out) ----------------
// out[v] = bf16( xb[v] + sum_{u in N(v)} xb[u] ), accumulate fp32
__global__ __launch_bounds__(256) void k_agg(const u16* __restrict__ xb,
                                             const int* __restrict__ row_start,
                                             const int* __restrict__ adj,
                                             u16* __restrict__ out) {
    int gid = blockIdx.x * blockDim.x + threadIdx.x;
    int node = gid >> 6, lane = gid & 63;
    if (node >= NN) return;
    const unsigned int* base = (const unsigned int*)xb;  // 64 dwords per row
    unsigned int selfv = base[(size_t)node * 64 + lane];
    float ax0 = bf_lo(selfv), ay0 = bf_hi(selfv);
    float ax1 = 0.f, ay1 = 0.f, ax2 = 0.f, ay2 = 0.f, ax3 = 0.f, ay3 = 0.f;
    int s = row_start[node], e = row_start[node + 1];
    int i = s;
    for (; i + 3 < e; i += 4) {
        unsigned int t0 = base[(size_t)adj[i] * 64 + lane];
        unsigned int t1 = base[(size_t)adj[i + 1] * 64 + lane];
        unsigned int t2 = base[(size_t)adj[i + 2] * 64 + lane];
        unsigned int t3 = base[(size_t)adj[i + 3] * 64 + lane];
        ax0 += bf_lo(t0); ay0 += bf_hi(t0);
        ax1 += bf_lo(t1); ay1 += bf_hi(t1);
        ax2 += bf_lo(t2); ay2 += bf_hi(t2);
        ax3 += bf_lo(t3); ay3 += bf_hi(t3);
    }
    for (; i < e; i++) {
        unsigned int t = base[(size_t)adj[i] * 64 + lane];
        ax0 += bf_lo(t); ay0 += bf_hi(t);
    }
    float ax = (ax0 + ax1) + (ax2 + ax3);
    float ay = (ay0 + ay1) + (ay2 + ay3);
    ((unsigned int*)out)[(size_t)node * 64 + lane] = bf_pack(ax, ay);
}

// ---------------- fused MLP (+LN+relu) per 128-node tile ----------------
template <bool LN, bool B16OUT>
__global__ __launch_bounds__(256) void k_mlp(const u16* __restrict__ hin,
                                             const u16* __restrict__ w1t,
                                             const float* __restrict__ b1,
                                             const u16* __restrict__ w2t,
                                             const float* __restrict__ b2,
                                             const float* __restrict__ g,
                                             const float* __restrict__ bta,
                                             void* __restrict__ hout) {
    __shared__ u16 lds[128 * LDSW];
    const int tid = threadIdx.x;
    const int wv = tid >> 6, lane = tid & 63;
    const int l15 = lane & 15, l4 = lane >> 4;
    const int tile0 = blockIdx.x * 128;

#pragma unroll
    for (int it = 0; it < 8; ++it) {
        int slot = tid + it * 256;
        int row = slot >> 4, c16 = slot & 15;
        u32x4 v = {0u, 0u, 0u, 0u};
        int grow = tile0 + row;
        if (grow < NN) v = *(const u32x4*)(hin + (size_t)grow * DD + c16 * 8);
        *(u32x4*)&lds[row * LDSW + c16 * 8] = v;
    }
    __syncthreads();

    float b1c[8], b2c[8], gc[8], bc[8];
#pragma unroll
    for (int c = 0; c < 8; c++) {
        int col = c * 16 + l15;
        b1c[c] = b1[col];
        b2c[c] = b2[col];
        if (LN) { gc[c] = g[col]; bc[c] = bta[col]; }
    }

    f32x4 acc[2][8];
#pragma unroll
    for (int r = 0; r < 2; r++)
#pragma unroll
        for (int c = 0; c < 8; c++) acc[r][c] = (f32x4){0.f, 0.f, 0.f, 0.f};

    const int rowbase = wv * 32;

    // GEMM1
#pragma unroll
    for (int ks = 0; ks < 4; ++ks) {
        bf16x8 a0 = __builtin_bit_cast(bf16x8,
            *(const u32x4*)&lds[(rowbase + l15) * LDSW + ks * 32 + l4 * 8]);
        bf16x8 a1 = __builtin_bit_cast(bf16x8,
            *(const u32x4*)&lds[(rowbase + 16 + l15) * LDSW + ks * 32 + l4 * 8]);
#pragma unroll
        for (int c = 0; c < 8; c++) {
            bf16x8 b = __builtin_bit_cast(bf16x8,
                *(const u32x4*)(w1t + (size_t)(c * 16 + l15) * DD + ks * 32 + l4 * 8));
            acc[0][c] = __builtin_amdgcn_mfma_f32_16x16x32_bf16(a0, b, acc[0][c], 0, 0, 0);
            acc[1][c] = __builtin_amdgcn_mfma_f32_16x16x32_bf16(a1, b, acc[1][c], 0, 0, 0);
        }
    }

    // h1 -> LDS (bf16, relu)
#pragma unroll
    for (int r = 0; r < 2; r++) {
#pragma unroll
        for (int c = 0; c < 8; c++) {
            int col = c * 16 + l15;
#pragma unroll
            for (int j = 0; j < 4; j++) {
                float v = acc[r][c][j] + b1c[c];
                v = v > 0.f ? v : 0.f;
                bf16 b = (bf16)v;
                int row = rowbase + r * 16 + l4 * 4 + j;
                lds[row * LDSW + col] = __builtin_bit_cast(u16, b);
            }
        }
    }
    __syncthreads();

#pragma unroll
    for (int r = 0; r < 2; r++)
#pragma unroll
        for (int c = 0; c < 8; c++) acc[r][c] = (f32x4){0.f, 0.f, 0.f, 0.f};

    // GEMM2
#pragma unroll
    for (int ks = 0; ks < 4; ++ks) {
        bf16x8 a0 = __builtin_bit_cast(bf16x8,
            *(const u32x4*)&lds[(rowbase + l15) * LDSW + ks * 32 + l4 * 8]);
        bf16x8 a1 = __builtin_bit_cast(bf16x8,
            *(const u32x4*)&lds[(rowbase + 16 + l15) * LDSW + ks * 32 + l4 * 8]);
#pragma unroll
        for (int c = 0; c < 8; c++) {
            bf16x8 b = __builtin_bit_cast(bf16x8,
                *(const u32x4*)(w2t + (size_t)(c * 16 + l15) * DD + ks * 32 + l4 * 8));
            acc[0][c] = __builtin_amdgcn_mfma_f32_16x16x32_bf16(a0, b, acc[0][c], 0, 0, 0);
            acc[1][c] = __builtin_amdgcn_mfma_f32_16x16x32_bf16(a1, b, acc[1][c], 0, 0, 0);
        }
    }

    // epilogue
#pragma unroll
    for (int r = 0; r < 2; r++) {
        float vals[8][4];
#pragma unroll
        for (int c = 0; c < 8; c++)
#pragma unroll
            for (int j = 0; j < 4; j++) vals[c][j] = acc[r][c][j] + b2c[c];

        if (LN) {
            float s[4], q[4];
#pragma unroll
            for (int j = 0; j < 4; j++) {
                s[j] = 0.f; q[j] = 0.f;
#pragma unroll
                for (int c = 0; c < 8; c++) {
                    s[j] += vals[c][j];
                    q[j] += vals[c][j] * vals[c][j];
                }
            }
#pragma unroll
            for (int m = 1; m <= 8; m <<= 1) {
#pragma unroll
                for (int j = 0; j < 4; j++) {
                    s[j] += __shfl_xor(s[j], m);
                    q[j] += __shfl_xor(q[j], m);
                }
            }
#pragma unroll
            for (int j = 0; j < 4; j++) {
                float mu = s[j] * (1.f / 128.f);
                float var = q[j] * (1.f / 128.f) - mu * mu;
                float rs = rsqrtf(var + 1e-5f);
#pragma unroll
                for (int c = 0; c < 8; c++) {
                    float v = (vals[c][j] - mu) * rs * gc[c] + bc[c];
                    vals[c][j] = v > 0.f ? v : 0.f;
                }
            }
        }

#pragma unroll
        for (int c = 0; c < 8; c++) {
            int col = c * 16 + l15;
#pragma unroll
            for (int j = 0; j < 4; j++) {
                int row = tile0 + rowbase + r * 16 + l4 * 4 + j;
                if (row < NN) {
                    if (B16OUT) {
                        ((u16*)hout)[(size_t)row * DD + col] =
                            __builtin_bit_cast(u16, (bf16)vals[c][j]);
                    } else {
                        ((float*)hout)[(size_t)row * DD + col] = vals[c][j];
                    }
                }
            }
        }
    }
}

// ---------------- launch ----------------
extern "C" void kernel_launch(void* const* d_in, const int* in_sizes, int n_in,
                              void* d_out, int out_size, void* d_ws, size_t ws_size,
                              hipStream_t stream) {
    const float* x = (const float*)d_in[0];
    const int* ei = (const int*)d_in[1];
    const float* w1[4]; const float* b1[4]; const float* w2[4]; const float* b2[4];
    for (int i = 0; i < 4; i++) {
        w1[i] = (const float*)d_in[2 + 4 * i];
        b1[i] = (const float*)d_in[3 + 4 * i];
        w2[i] = (const float*)d_in[4 + 4 * i];
        b2[i] = (const float*)d_in[5 + 4 * i];
    }
    const float* g[3]; const float* bt[3];
    for (int i = 0; i < 3; i++) {
        g[i] = (const float*)d_in[18 + 2 * i];
        bt[i] = (const float*)d_in[19 + 2 * i];
    }

    char* ws = (char*)d_ws;
    size_t off = 0;
    auto alloc = [&](size_t bytes) -> char* {
        char* p = ws + off;
        off = (off + bytes + 255) & ~(size_t)255;
        return p;
    };
    int* flag      = (int*)alloc(4);
    int* row_start = (int*)alloc((NN + 1) * 4);
    int* deg       = (int*)alloc(NN * 4);
    int* cursor    = (int*)alloc(NN * 4);
    int* adj       = (int*)alloc(NE * 4);
    int* partial   = (int*)alloc(NCH * 4);
    int* chunk_off = (int*)alloc(NCH * 4);
    u16* wt        = (u16*)alloc((size_t)8 * DD * DD * 2);
    u16* xb        = (u16*)alloc((size_t)NN * DD * 2);
    u16* hbf       = (u16*)alloc((size_t)NN * DD * 2);
    u16* hA        = (u16*)alloc((size_t)NN * DD * 2);
    u16* hB        = (u16*)alloc((size_t)NN * DD * 2);

    hipMemsetAsync(deg, 0, NN * 4, stream);
    k_detect<<<1, 256, 0, stream>>>(ei, flag);
    k_degree<<<(NE + 255) / 256, 256, 0, stream>>>(ei, flag, deg);
    k_scan1<<<NCH, 256, 0, stream>>>(deg, partial);
    k_scan2<<<1, 256, 0, stream>>>(partial, chunk_off);
    k_scan3<<<NCH, 256, 0, stream>>>(deg, chunk_off, row_start, cursor);
    k_fill<<<(NE + 255) / 256, 256, 0, stream>>>(ei, flag, cursor, adj);
    k_xconv<<<(NN * DD / 4 + 255) / 256, 256, 0, stream>>>(x, xb);

    Ptr8 p8;
    for (int i = 0; i < 4; i++) {
        p8.p[2 * i] = w1[i];
        p8.p[2 * i + 1] = w2[i];
    }
    k_wconv<<<dim3(128, 8), 128, 0, stream>>>(p8, wt);

    const u16* hin = xb;
    for (int i = 0; i < 4; i++) {
        k_agg<<<(NN * 64 + 255) / 256, 256, 0, stream>>>(hin, row_start, adj, hbf);
        const u16* w1ti = wt + (size_t)(2 * i) * DD * DD;
        const u16* w2ti = wt + (size_t)(2 * i + 1) * DD * DD;
        if (i < 3) {
            u16* outp = (i & 1) ? hB : hA;
            k_mlp<true, true><<<(NN + 127) / 128, 256, 0, stream>>>(
                hbf, w1ti, b1[i], w2ti, b2[i], g[i], bt[i], outp);
            hin = outp;
        } else {
            k_mlp<false, false><<<(NN + 127) / 128, 256, 0, stream>>>(
                hbf, w1ti, b1[i], w2ti, b2[i], nullptr, nullptr, d_out);
        }
    }
}

// Round 4
// 276.253 us; speedup vs baseline: 1.8111x; 1.1012x over previous
//
#include <hip/hip_runtime.h>
#include <hip/hip_bf16.h>

#define NN 50000
#define NE 600000
#define DD 128
#define LDSW 136
#define SC 256
#define NCH ((NN + SC - 1) / SC)  // 196

typedef __bf16 bf16;
typedef __attribute__((ext_vector_type(8))) __bf16 bf16x8;
typedef __attribute__((ext_vector_type(4))) float f32x4;
typedef __attribute__((ext_vector_type(4))) unsigned int u32x4;
typedef __attribute__((ext_vector_type(4))) unsigned short u16x4;
typedef unsigned short u16;

__device__ __forceinline__ float bf_lo(unsigned int u) {
    return __builtin_bit_cast(float, u << 16);
}
__device__ __forceinline__ float bf_hi(unsigned int u) {
    return __builtin_bit_cast(float, u & 0xffff0000u);
}
__device__ __forceinline__ unsigned int bf_pack(float x, float y) {
    u16 a = __builtin_bit_cast(u16, (bf16)x);
    u16 b = __builtin_bit_cast(u16, (bf16)y);
    return (unsigned int)a | ((unsigned int)b << 16);
}

struct Ptr8 { const float* p[8]; };

__device__ __forceinline__ int edge_dst(const int* ei, int e, int f) {
    return f ? ei[2 * NE + 2 * e] : ei[NE + e];
}
__device__ __forceinline__ int edge_src(const int* ei, int e, int f) {
    return f ? ei[2 * e] : ei[e];
}

// ---------------- fused init: deg=0, detect, x->bf16, w->bf16^T ----------------
#define J0 50000                 // deg zero
#define J1 (J0 + NN * DD / 4)    // xconv, 4 floats per id  -> 450000
#define J2 (J1 + 8 * DD * DD)    // wconv, 1 elem per id    -> 581072

__global__ __launch_bounds__(256) void k_init(const float* __restrict__ x,
                                              u16* __restrict__ xb,
                                              Ptr8 ws, u16* __restrict__ wt,
                                              int* __restrict__ deg,
                                              const int* __restrict__ ei,
                                              int* __restrict__ flag) {
    int tid = threadIdx.x;
    if (blockIdx.x == 0) {
        if (tid == 0) flag[0] = 1;          // assume int64 layout
        __syncthreads();
        if (ei[2 * tid + 1] != 0) flag[0] = 0;  // any nonzero odd word => int32
    }
    int id = blockIdx.x * 256 + tid;
    if (id < J0) {
        deg[id] = 0;
    } else if (id < J1) {
        int i = id - J0;
        f32x4 v = *(const f32x4*)(x + (size_t)i * 4);
        u16x4 o;
        o.x = __builtin_bit_cast(u16, (bf16)v.x);
        o.y = __builtin_bit_cast(u16, (bf16)v.y);
        o.z = __builtin_bit_cast(u16, (bf16)v.z);
        o.w = __builtin_bit_cast(u16, (bf16)v.w);
        *(u16x4*)(xb + (size_t)i * 4) = o;
    } else if (id < J2) {
        int i = id - J1;
        int m = i >> 14;          // matrix
        int rem = i & 16383;
        int k = rem >> 7;
        int n = rem & 127;        // consecutive ids -> consecutive n (coalesced read)
        bf16 b = (bf16)ws.p[m][k * DD + n];
        wt[(size_t)m * DD * DD + n * DD + k] = __builtin_bit_cast(u16, b);
    }
}

// ---------------- CSR build ----------------
__global__ void k_degree(const int* __restrict__ ei, const int* __restrict__ flag,
                         int* __restrict__ deg) {
    int i = blockIdx.x * blockDim.x + threadIdx.x;
    if (i < NE) {
        int f = flag[0];
        atomicAdd(&deg[edge_dst(ei, i, f)], 1);
    }
}

__global__ __launch_bounds__(256) void k_scan1(const int* __restrict__ deg,
                                               int* __restrict__ partial) {
    int b = blockIdx.x, tid = threadIdx.x;
    int i = b * SC + tid;
    int v = (i < NN) ? deg[i] : 0;
#pragma unroll
    for (int off = 1; off < 64; off <<= 1) v += __shfl_xor(v, off);
    __shared__ int sm[4];
    if ((tid & 63) == 0) sm[tid >> 6] = v;
    __syncthreads();
    if (tid == 0) partial[b] = sm[0] + sm[1] + sm[2] + sm[3];
}

__global__ __launch_bounds__(256) void k_scan2(const int* __restrict__ partial,
                                               int* __restrict__ chunk_off) {
    int tid = threadIdx.x;
    int lane = tid & 63, w = tid >> 6;
    int v = (tid < NCH) ? partial[tid] : 0;
    int orig = v;
#pragma unroll
    for (int off = 1; off < 64; off <<= 1) {
        int t = __shfl_up(v, off);
        if (lane >= off) v += t;
    }
    __shared__ int sm[4];
    if (lane == 63) sm[w] = v;
    __syncthreads();
    int add = 0;
    for (int k = 0; k < w; k++) add += sm[k];
    v += add;
    if (tid < NCH) chunk_off[tid] = v - orig;  // exclusive prefix
}

__global__ __launch_bounds__(256) void k_scan3(const int* __restrict__ deg,
                                               const int* __restrict__ chunk_off,
                                               int* __restrict__ row_start,
                                               int* __restrict__ cursor) {
    int b = blockIdx.x, tid = threadIdx.x;
    int i = b * SC + tid;
    int lane = tid & 63, w = tid >> 6;
    int v = (i < NN) ? deg[i] : 0;
    int orig = v;
#pragma unroll
    for (int off = 1; off < 64; off <<= 1) {
        int t = __shfl_up(v, off);
        if (lane >= off) v += t;
    }
    __shared__ int sm[4];
    if (lane == 63) sm[w] = v;
    __syncthreads();
    int add = chunk_off[b];
    for (int k = 0; k < w; k++) add += sm[k];
    int ex = v - orig + add;
    if (i < NN) { row_start[i] = ex; cursor[i] = ex; }
    if (b == 0 && tid == 0) row_start[NN] = NE;
}

__global__ void k_fill(const int* __restrict__ ei, const int* __restrict__ flag,
                       int* __restrict__ cursor, int* __restrict__ adj) {
    int i = blockIdx.x * blockDim.x + threadIdx.x;
    if (i < NE) {
        int f = flag[0];
        int d = edge_dst(ei, i, f);
        int p = atomicAdd(&cursor[d], 1);
        adj[p] = edge_src(ei, i, f);
    }
}

// ---------------- aggregation: 4 nodes per wave, 16 lanes x 16B per row ----------------
__global__ __launch_bounds__(256) void k_agg(const u16* __restrict__ xb,
                                             const int* __restrict__ row_start,
                                             const int* __restrict__ adj,
                                             u16* __restrict__ out) {
    int gid = blockIdx.x * blockDim.x + threadIdx.x;
    int wave = gid >> 6, lane = gid & 63;
    int g = lane >> 4, l = lane & 15;
    int node = wave * 4 + g;
    if (node >= NN) return;
    const u32x4* base = (const u32x4*)xb;  // 16 x dwordx4 per row
    u32x4 sv = base[(size_t)node * 16 + l];
    float af[8];
#pragma unroll
    for (int j = 0; j < 4; j++) { af[2 * j] = bf_lo(sv[j]); af[2 * j + 1] = bf_hi(sv[j]); }
    int s = row_start[node], e = row_start[node + 1];
    int i = s;
    for (; i + 1 < e; i += 2) {
        u32x4 t0 = base[(size_t)adj[i] * 16 + l];
        u32x4 t1 = base[(size_t)adj[i + 1] * 16 + l];
#pragma unroll
        for (int j = 0; j < 4; j++) {
            af[2 * j]     += bf_lo(t0[j]) + bf_lo(t1[j]);
            af[2 * j + 1] += bf_hi(t0[j]) + bf_hi(t1[j]);
        }
    }
    if (i < e) {
        u32x4 t = base[(size_t)adj[i] * 16 + l];
#pragma unroll
        for (int j = 0; j < 4; j++) { af[2 * j] += bf_lo(t[j]); af[2 * j + 1] += bf_hi(t[j]); }
    }
    u32x4 o;
#pragma unroll
    for (int j = 0; j < 4; j++) o[j] = bf_pack(af[2 * j], af[2 * j + 1]);
    ((u32x4*)out)[(size_t)node * 16 + l] = o;
}

// ---------------- fused MLP (+LN+relu) per 128-node tile ----------------
template <bool LN, bool B16OUT>
__global__ __launch_bounds__(256) void k_mlp(const u16* __restrict__ hin,
                                             const u16* __restrict__ w1t,
                                             const float* __restrict__ b1,
                                             const u16* __restrict__ w2t,
                                             const float* __restrict__ b2,
                                             const float* __restrict__ g,
                                             const float* __restrict__ bta,
                                             void* __restrict__ hout) {
    __shared__ u16 lds[128 * LDSW];
    const int tid = threadIdx.x;
    const int wv = tid >> 6, lane = tid & 63;
    const int l15 = lane & 15, l4 = lane >> 4;
    const int tile0 = blockIdx.x * 128;

#pragma unroll
    for (int it = 0; it < 8; ++it) {
        int slot = tid + it * 256;
        int row = slot >> 4, c16 = slot & 15;
        u32x4 v = {0u, 0u, 0u, 0u};
        int grow = tile0 + row;
        if (grow < NN) v = *(const u32x4*)(hin + (size_t)grow * DD + c16 * 8);
        *(u32x4*)&lds[row * LDSW + c16 * 8] = v;
    }
    __syncthreads();

    float b1c[8], b2c[8], gc[8], bc[8];
#pragma unroll
    for (int c = 0; c < 8; c++) {
        int col = c * 16 + l15;
        b1c[c] = b1[col];
        b2c[c] = b2[col];
        if (LN) { gc[c] = g[col]; bc[c] = bta[col]; }
    }

    f32x4 acc[2][8];
#pragma unroll
    for (int r = 0; r < 2; r++)
#pragma unroll
        for (int c = 0; c < 8; c++) acc[r][c] = (f32x4){0.f, 0.f, 0.f, 0.f};

    const int rowbase = wv * 32;

    // GEMM1
#pragma unroll
    for (int ks = 0; ks < 4; ++ks) {
        bf16x8 a0 = __builtin_bit_cast(bf16x8,
            *(const u32x4*)&lds[(rowbase + l15) * LDSW + ks * 32 + l4 * 8]);
        bf16x8 a1 = __builtin_bit_cast(bf16x8,
            *(const u32x4*)&lds[(rowbase + 16 + l15) * LDSW + ks * 32 + l4 * 8]);
#pragma unroll
        for (int c = 0; c < 8; c++) {
            bf16x8 b = __builtin_bit_cast(bf16x8,
                *(const u32x4*)(w1t + (size_t)(c * 16 + l15) * DD + ks * 32 + l4 * 8));
            acc[0][c] = __builtin_amdgcn_mfma_f32_16x16x32_bf16(a0, b, acc[0][c], 0, 0, 0);
            acc[1][c] = __builtin_amdgcn_mfma_f32_16x16x32_bf16(a1, b, acc[1][c], 0, 0, 0);
        }
    }

    // h1 -> LDS (bf16, relu)
#pragma unroll
    for (int r = 0; r < 2; r++) {
#pragma unroll
        for (int c = 0; c < 8; c++) {
            int col = c * 16 + l15;
#pragma unroll
            for (int j = 0; j < 4; j++) {
                float v = acc[r][c][j] + b1c[c];
                v = v > 0.f ? v : 0.f;
                bf16 b = (bf16)v;
                int row = rowbase + r * 16 + l4 * 4 + j;
                lds[row * LDSW + col] = __builtin_bit_cast(u16, b);
            }
        }
    }
    __syncthreads();

#pragma unroll
    for (int r = 0; r < 2; r++)
#pragma unroll
        for (int c = 0; c < 8; c++) acc[r][c] = (f32x4){0.f, 0.f, 0.f, 0.f};

    // GEMM2
#pragma unroll
    for (int ks = 0; ks < 4; ++ks) {
        bf16x8 a0 = __builtin_bit_cast(bf16x8,
            *(const u32x4*)&lds[(rowbase + l15) * LDSW + ks * 32 + l4 * 8]);
        bf16x8 a1 = __builtin_bit_cast(bf16x8,
            *(const u32x4*)&lds[(rowbase + 16 + l15) * LDSW + ks * 32 + l4 * 8]);
#pragma unroll
        for (int c = 0; c < 8; c++) {
            bf16x8 b = __builtin_bit_cast(bf16x8,
                *(const u32x4*)(w2t + (size_t)(c * 16 + l15) * DD + ks * 32 + l4 * 8));
            acc[0][c] = __builtin_amdgcn_mfma_f32_16x16x32_bf16(a0, b, acc[0][c], 0, 0, 0);
            acc[1][c] = __builtin_amdgcn_mfma_f32_16x16x32_bf16(a1, b, acc[1][c], 0, 0, 0);
        }
    }

    // epilogue
#pragma unroll
    for (int r = 0; r < 2; r++) {
        float vals[8][4];
#pragma unroll
        for (int c = 0; c < 8; c++)
#pragma unroll
            for (int j = 0; j < 4; j++) vals[c][j] = acc[r][c][j] + b2c[c];

        if (LN) {
            float s[4], q[4];
#pragma unroll
            for (int j = 0; j < 4; j++) {
                s[j] = 0.f; q[j] = 0.f;
#pragma unroll
                for (int c = 0; c < 8; c++) {
                    s[j] += vals[c][j];
                    q[j] += vals[c][j] * vals[c][j];
                }
            }
#pragma unroll
            for (int m = 1; m <= 8; m <<= 1) {
#pragma unroll
                for (int j = 0; j < 4; j++) {
                    s[j] += __shfl_xor(s[j], m);
                    q[j] += __shfl_xor(q[j], m);
                }
            }
#pragma unroll
            for (int j = 0; j < 4; j++) {
                float mu = s[j] * (1.f / 128.f);
                float var = q[j] * (1.f / 128.f) - mu * mu;
                float rs = rsqrtf(var + 1e-5f);
#pragma unroll
                for (int c = 0; c < 8; c++) {
                    float v = (vals[c][j] - mu) * rs * gc[c] + bc[c];
                    vals[c][j] = v > 0.f ? v : 0.f;
                }
            }
        }

#pragma unroll
        for (int c = 0; c < 8; c++) {
            int col = c * 16 + l15;
#pragma unroll
            for (int j = 0; j < 4; j++) {
                int row = tile0 + rowbase + r * 16 + l4 * 4 + j;
                if (row < NN) {
                    if (B16OUT) {
                        ((u16*)hout)[(size_t)row * DD + col] =
                            __builtin_bit_cast(u16, (bf16)vals[c][j]);
                    } else {
                        ((float*)hout)[(size_t)row * DD + col] = vals[c][j];
                    }
                }
            }
        }
    }
}

// ---------------- launch ----------------
extern "C" void kernel_launch(void* const* d_in, const int* in_sizes, int n_in,
                              void* d_out, int out_size, void* d_ws, size_t ws_size,
                              hipStream_t stream) {
    const float* x = (const float*)d_in[0];
    const int* ei = (const int*)d_in[1];
    const float* w1[4]; const float* b1[4]; const float* w2[4]; const float* b2[4];
    for (int i = 0; i < 4; i++) {
        w1[i] = (const float*)d_in[2 + 4 * i];
        b1[i] = (const float*)d_in[3 + 4 * i];
        w2[i] = (const float*)d_in[4 + 4 * i];
        b2[i] = (const float*)d_in[5 + 4 * i];
    }
    const float* g[3]; const float* bt[3];
    for (int i = 0; i < 3; i++) {
        g[i] = (const float*)d_in[18 + 2 * i];
        bt[i] = (const float*)d_in[19 + 2 * i];
    }

    char* ws = (char*)d_ws;
    size_t off = 0;
    auto alloc = [&](size_t bytes) -> char* {
        char* p = ws + off;
        off = (off + bytes + 255) & ~(size_t)255;
        return p;
    };
    int* flag      = (int*)alloc(4);
    int* row_start = (int*)alloc((NN + 1) * 4);
    int* deg       = (int*)alloc(NN * 4);
    int* cursor    = (int*)alloc(NN * 4);
    int* adj       = (int*)alloc(NE * 4);
    int* partial   = (int*)alloc(NCH * 4);
    int* chunk_off = (int*)alloc(NCH * 4);
    u16* wt        = (u16*)alloc((size_t)8 * DD * DD * 2);
    u16* xb        = (u16*)alloc((size_t)NN * DD * 2);
    u16* hbf       = (u16*)alloc((size_t)NN * DD * 2);
    u16* hA        = (u16*)alloc((size_t)NN * DD * 2);
    u16* hB        = (u16*)alloc((size_t)NN * DD * 2);

    Ptr8 p8;
    for (int i = 0; i < 4; i++) {
        p8.p[2 * i] = w1[i];
        p8.p[2 * i + 1] = w2[i];
    }

    k_init<<<(J2 + 255) / 256, 256, 0, stream>>>(x, xb, p8, wt, deg, ei, flag);
    k_degree<<<(NE + 255) / 256, 256, 0, stream>>>(ei, flag, deg);
    k_scan1<<<NCH, 256, 0, stream>>>(deg, partial);
    k_scan2<<<1, 256, 0, stream>>>(partial, chunk_off);
    k_scan3<<<NCH, 256, 0, stream>>>(deg, chunk_off, row_start, cursor);
    k_fill<<<(NE + 255) / 256, 256, 0, stream>>>(ei, flag, cursor, adj);

    const u16* hin = xb;
    for (int i = 0; i < 4; i++) {
        k_agg<<<(NN / 4 * 64 + 255) / 256, 256, 0, stream>>>(hin, row_start, adj, hbf);
        const u16* w1ti = wt + (size_t)(2 * i) * DD * DD;
        const u16* w2ti = wt + (size_t)(2 * i + 1) * DD * DD;
        if (i < 3) {
            u16* outp = (i & 1) ? hB : hA;
            k_mlp<true, true><<<(NN + 127) / 128, 256, 0, stream>>>(
                hbf, w1ti, b1[i], w2ti, b2[i], g[i], bt[i], outp);
            hin = outp;
        } else {
            k_mlp<false, false><<<(NN + 127) / 128, 256, 0, stream>>>(
                hbf, w1ti, b1[i], w2ti, b2[i], nullptr, nullptr, d_out);
        }
    }
}